// Round 1
// baseline (366.428 us; speedup 1.0000x reference)
//
#include <hip/hip_runtime.h>
#include <hip/hip_bf16.h>

#define Bn 16
#define Cn 512
#define Nn 4096

typedef unsigned short u16;
typedef __bf16 bf16x8 __attribute__((ext_vector_type(8)));
typedef float f32x4 __attribute__((ext_vector_type(4)));

__device__ __forceinline__ u16 f2bf(float f) {
    __hip_bfloat16 h = __float2bfloat16(f);
    return *reinterpret_cast<u16*>(&h);
}

// ---------------------------------------------------------------------------
// K1: x (B,C,N) fp32 -> x_t (B,N,C) bf16, plus per-(b,c) partial sums over the
// 64-wide n-tile (deterministic reduction, no atomics).
// ---------------------------------------------------------------------------
__global__ __launch_bounds__(256) void k_transpose(
    const float* __restrict__ x, u16* __restrict__ xt, float* __restrict__ sxp)
{
    __shared__ float tile[64 * 65];
    const int b = blockIdx.z, c0 = blockIdx.y * 64, n0 = blockIdx.x * 64;
    const int t = threadIdx.x;
    const float* xb = x + ((size_t)(b * Cn + c0)) * Nn + n0;

    float part[4];
#pragma unroll
    for (int r = 0; r < 4; ++r) {
        int cl = (t >> 4) + r * 16;
        int nl = (t & 15) * 4;
        float4 v = *(const float4*)(xb + (size_t)cl * Nn + nl);
        float* tp = &tile[cl * 65 + nl];
        tp[0] = v.x; tp[1] = v.y; tp[2] = v.z; tp[3] = v.w;
        part[r] = (v.x + v.y) + (v.z + v.w);
    }
#pragma unroll
    for (int m = 1; m < 16; m <<= 1) {
#pragma unroll
        for (int r = 0; r < 4; ++r) part[r] += __shfl_xor(part[r], m);
    }
    if ((t & 15) == 0) {
#pragma unroll
        for (int r = 0; r < 4; ++r) {
            int cl = (t >> 4) + r * 16;
            sxp[(size_t)(b * Cn + c0 + cl) * 64 + blockIdx.x] = part[r];
        }
    }
    __syncthreads();
    u16* xtb = xt + ((size_t)(b * Nn + n0)) * Cn + c0;
#pragma unroll
    for (int r = 0; r < 4; ++r) {
        int nl = (t >> 4) + r * 16;
        int c4 = (t & 15) * 4;
        ushort4 h;
        h.x = f2bf(tile[(c4 + 0) * 65 + nl]);
        h.y = f2bf(tile[(c4 + 1) * 65 + nl]);
        h.z = f2bf(tile[(c4 + 2) * 65 + nl]);
        h.w = f2bf(tile[(c4 + 3) * 65 + nl]);
        *(ushort4*)(xtb + (size_t)nl * Cn + c4) = h;
    }
}

// K1b: reduce 64 n-tile partials -> Sx[b*C+c]
__global__ __launch_bounds__(256) void k_sxred(
    const float* __restrict__ sxp, float* __restrict__ sx)
{
    int i = blockIdx.x * 256 + threadIdx.x;  // 0..8191
    const float* p = sxp + (size_t)i * 64;
    float s = 0.f;
#pragma unroll
    for (int j = 0; j < 64; ++j) s += p[j];
    sx[i] = s;
}

// K2: qy[b,o] = wq@y + bq ; sk[b,o] = wk@Sx + N*bk. One wave per output.
__global__ __launch_bounds__(256) void k_qk(
    const float* __restrict__ wq, const float* __restrict__ bq,
    const float* __restrict__ wk, const float* __restrict__ bk,
    const float* __restrict__ y, const float* __restrict__ sx,
    float* __restrict__ qy, float* __restrict__ sk)
{
    const int w = threadIdx.x >> 6, lane = threadIdx.x & 63;
    const int o = blockIdx.x * 4 + w;
    const int b = blockIdx.y;
    const int mode = blockIdx.z;
    const float* W = mode ? wk : wq;
    const float* vec = mode ? (sx + b * Cn) : (y + b * Cn);
    float sum = 0.f;
#pragma unroll
    for (int i = 0; i < 8; ++i) {
        int k2 = lane + i * 64;
        sum += W[(size_t)o * Cn + k2] * vec[k2];
    }
#pragma unroll
    for (int m = 1; m < 64; m <<= 1) sum += __shfl_xor(sum, m);
    if (lane == 0) {
        if (mode) sk[b * Cn + o] = sum + 4096.0f * bk[o];
        else      qy[b * Cn + o] = sum + bq[o];
    }
}

// K2b: wv_t[e,d] = bf16(wv[d,e])
__global__ __launch_bounds__(256) void k_wvt(
    const float* __restrict__ wv, u16* __restrict__ wvt)
{
    int idx = blockIdx.x * 256 + threadIdx.x;   // e*512 + d
    int e = idx >> 9, d = idx & 511;
    wvt[idx] = f2bf(wv[(size_t)d * Cn + e]);
}

// K3: per (b,c) row: softmax_d(qy*sk) -> attn (bf16), beff = attn . bv (fp32)
__global__ __launch_bounds__(256) void k_softmax(
    const float* __restrict__ qy, const float* __restrict__ sk,
    const float* __restrict__ bv, u16* __restrict__ attn,
    float* __restrict__ beff)
{
    __shared__ float red[4], red2[4], red3[4];
    const int b = blockIdx.x >> 9, c = blockIdx.x & 511;
    const int t = threadIdx.x;
    const float q = qy[b * Cn + c];
    const float l0 = q * sk[b * Cn + t];
    const float l1 = q * sk[b * Cn + t + 256];
    float mx = fmaxf(l0, l1);
#pragma unroll
    for (int m = 1; m < 64; m <<= 1) mx = fmaxf(mx, __shfl_xor(mx, m));
    if ((t & 63) == 0) red[t >> 6] = mx;
    __syncthreads();
    mx = fmaxf(fmaxf(red[0], red[1]), fmaxf(red[2], red[3]));
    const float e0 = __expf(l0 - mx), e1 = __expf(l1 - mx);
    float s = e0 + e1;
#pragma unroll
    for (int m = 1; m < 64; m <<= 1) s += __shfl_xor(s, m);
    if ((t & 63) == 0) red2[t >> 6] = s;
    __syncthreads();
    s = red2[0] + red2[1] + red2[2] + red2[3];
    const float inv = 1.0f / s;
    const float a0 = e0 * inv, a1 = e1 * inv;
    u16* arow = attn + ((size_t)(b * Cn + c)) * Cn;
    arow[t] = f2bf(a0);
    arow[t + 256] = f2bf(a1);
    float pb = a0 * bv[t] + a1 * bv[t + 256];
#pragma unroll
    for (int m = 1; m < 64; m <<= 1) pb += __shfl_xor(pb, m);
    if ((t & 63) == 0) red3[t >> 6] = pb;
    __syncthreads();
    if (t == 0) beff[b * Cn + c] = red3[0] + red3[1] + red3[2] + red3[3];
}

// ---------------------------------------------------------------------------
// Shared MFMA GEMM: D[b] = A[b] (MxK, bf16, lda=K) * Bt[b]^T (Bt is NxK, bf16).
// 128x128 block tile, BK=32, 4 waves each 64x64 (4x4 of 16x16x32 MFMA).
// FINAL=1: out fp32 = gamma*(acc + beff[row]) + xres ; else out bf16.
// ---------------------------------------------------------------------------
template <int FINAL>
__global__ __launch_bounds__(256) void k_gemm(
    const u16* __restrict__ A, size_t strideA,
    const u16* __restrict__ Bt, size_t strideB,
    int N,
    u16* __restrict__ outBf, size_t strideOb,
    float* __restrict__ outF,
    const float* __restrict__ xres,
    const float* __restrict__ beff,
    const float* __restrict__ gamma)
{
    constexpr int K = 512;
    __shared__ u16 la[128 * 32];
    __shared__ u16 lb[128 * 32];
    const int b = blockIdx.z;
    const int m0 = blockIdx.y * 128;
    const int n0 = blockIdx.x * 128;
    A  += (size_t)b * strideA;
    Bt += (size_t)b * strideB;
    const int t = threadIdx.x;
    const int lane = t & 63;
    const int w = t >> 6;
    const int wm = (w >> 1) * 64, wn = (w & 1) * 64;
    const int l15 = lane & 15, quad = lane >> 4;

    f32x4 acc[4][4];
#pragma unroll
    for (int i = 0; i < 4; ++i)
#pragma unroll
        for (int j = 0; j < 4; ++j)
            acc[i][j] = (f32x4){0.f, 0.f, 0.f, 0.f};

    const int srow = t >> 2;        // 0..63
    const int scol = (t & 3) * 8;   // 0,8,16,24  (bf16 elements)

    for (int k0 = 0; k0 < K; k0 += 32) {
        __syncthreads();
        *(uint4*)&la[srow * 32 + scol] =
            *(const uint4*)(A + (size_t)(m0 + srow) * K + k0 + scol);
        *(uint4*)&la[(srow + 64) * 32 + scol] =
            *(const uint4*)(A + (size_t)(m0 + srow + 64) * K + k0 + scol);
        *(uint4*)&lb[srow * 32 + scol] =
            *(const uint4*)(Bt + (size_t)(n0 + srow) * K + k0 + scol);
        *(uint4*)&lb[(srow + 64) * 32 + scol] =
            *(const uint4*)(Bt + (size_t)(n0 + srow + 64) * K + k0 + scol);
        __syncthreads();

        bf16x8 af[4], bfr[4];
#pragma unroll
        for (int mi = 0; mi < 4; ++mi)
            af[mi] = *(const bf16x8*)&la[(wm + mi * 16 + l15) * 32 + quad * 8];
#pragma unroll
        for (int ni = 0; ni < 4; ++ni)
            bfr[ni] = *(const bf16x8*)&lb[(wn + ni * 16 + l15) * 32 + quad * 8];
#pragma unroll
        for (int mi = 0; mi < 4; ++mi)
#pragma unroll
            for (int ni = 0; ni < 4; ++ni)
                acc[mi][ni] = __builtin_amdgcn_mfma_f32_16x16x32_bf16(
                    af[mi], bfr[ni], acc[mi][ni], 0, 0, 0);
    }

    if (FINAL) {
        const float g = gamma[0];
#pragma unroll
        for (int mi = 0; mi < 4; ++mi) {
#pragma unroll
            for (int reg = 0; reg < 4; ++reg) {
                const int r = m0 + wm + mi * 16 + quad * 4 + reg;
                const float be = beff[b * Cn + r];
                const size_t base = ((size_t)(b * Cn + r)) * N;
#pragma unroll
                for (int ni = 0; ni < 4; ++ni) {
                    const int cidx = n0 + wn + ni * 16 + l15;
                    outF[base + cidx] = g * (acc[mi][ni][reg] + be) + xres[base + cidx];
                }
            }
        }
    } else {
#pragma unroll
        for (int mi = 0; mi < 4; ++mi) {
#pragma unroll
            for (int reg = 0; reg < 4; ++reg) {
                const int r = m0 + wm + mi * 16 + quad * 4 + reg;
                const size_t base = (size_t)b * strideOb + (size_t)r * N;
#pragma unroll
                for (int ni = 0; ni < 4; ++ni) {
                    const int cidx = n0 + wn + ni * 16 + l15;
                    outBf[base + cidx] = f2bf(acc[mi][ni][reg]);
                }
            }
        }
    }
}

// ---------------------------------------------------------------------------
extern "C" void kernel_launch(void* const* d_in, const int* in_sizes, int n_in,
                              void* d_out, int out_size, void* d_ws, size_t ws_size,
                              hipStream_t stream)
{
    const float* x     = (const float*)d_in[0];
    const float* y     = (const float*)d_in[1];
    const float* wq    = (const float*)d_in[2];
    const float* bq    = (const float*)d_in[3];
    const float* wk    = (const float*)d_in[4];
    const float* bk    = (const float*)d_in[5];
    const float* wv    = (const float*)d_in[6];
    const float* bv    = (const float*)d_in[7];
    const float* gamma = (const float*)d_in[8];
    float* out = (float*)d_out;

    char* ws = (char*)d_ws;
    u16*   xt   = (u16*)  (ws + 0);           // 67,108,864 B : x^T bf16 (B,N,C)
    float* sxp  = (float*)(ws + 67108864);    //  2,097,152 B : partial sums
    float* sx   = (float*)(ws + 69206016);    //     32,768 B
    float* qy   = (float*)(ws + 69238784);    //     32,768 B
    float* sk   = (float*)(ws + 69271552);    //     32,768 B
    float* beff = (float*)(ws + 69304320);    //     32,768 B
    u16*   attn = (u16*)  (ws + 69337088);    //  8,388,608 B : attn bf16
    u16*   wvt  = (u16*)  (ws + 77725696);    //    524,288 B : wv^T bf16
    u16*   weff = (u16*)  (ws + 78249984);    //  8,388,608 B : Weff bf16
    // total ~86.6 MB

    k_transpose<<<dim3(64, 8, Bn), dim3(256), 0, stream>>>(x, xt, sxp);
    k_sxred<<<dim3(32), dim3(256), 0, stream>>>(sxp, sx);
    k_wvt<<<dim3(1024), dim3(256), 0, stream>>>(wv, wvt);
    k_qk<<<dim3(128, Bn, 2), dim3(256), 0, stream>>>(wq, bq, wk, bk, y, sx, qy, sk);
    k_softmax<<<dim3(Bn * Cn), dim3(256), 0, stream>>>(qy, sk, bv, attn, beff);
    // Weff[b] = attn[b] @ wv  (as A * wv_t^T), output bf16
    k_gemm<0><<<dim3(4, 4, Bn), dim3(256), 0, stream>>>(
        attn, (size_t)Cn * Cn, wvt, (size_t)0, Cn,
        weff, (size_t)Cn * Cn, nullptr, nullptr, nullptr, nullptr);
    // out[b] = gamma * (Weff[b] @ x[b] + beff) + x
    k_gemm<1><<<dim3(32, 4, Bn), dim3(256), 0, stream>>>(
        weff, (size_t)Cn * Cn, xt, (size_t)Nn * Cn, Nn,
        nullptr, (size_t)0, out, x, beff, gamma);
}

// Round 2
// 361.144 us; speedup vs baseline: 1.0146x; 1.0146x over previous
//
#include <hip/hip_runtime.h>
#include <hip/hip_bf16.h>

#define Bn 16
#define Cn 512
#define Nn 4096

typedef unsigned short u16;
typedef __bf16 bf16x8 __attribute__((ext_vector_type(8)));
typedef float f32x4 __attribute__((ext_vector_type(4)));
typedef unsigned short u16x8 __attribute__((ext_vector_type(8)));

__device__ __forceinline__ u16 f2bf(float f) {
    __hip_bfloat16 h = __float2bfloat16(f);
    return *reinterpret_cast<u16*>(&h);
}

// async global->LDS, 16B per lane; LDS dest is wave-uniform base + lane*16
__device__ __forceinline__ void glds16(const u16* g, u16* l) {
    __builtin_amdgcn_global_load_lds(
        (const __attribute__((address_space(1))) void*)g,
        (__attribute__((address_space(3))) void*)l, 16, 0, 0);
}

// ---------------------------------------------------------------------------
// K1: x (B,C,N) fp32 -> x_t (B,N,C) bf16, plus per-(b,c) partial sums over the
// 64-wide n-tile. 128c x 64n tile: 256B segments on both read and write sides.
// ---------------------------------------------------------------------------
__global__ __launch_bounds__(256) void k_transpose(
    const float* __restrict__ x, u16* __restrict__ xt, float* __restrict__ sxp)
{
    __shared__ float tile[128 * 65];
    const int b = blockIdx.z, c0 = blockIdx.y * 128, n0 = blockIdx.x * 64;
    const int t = threadIdx.x;
    const float* xb = x + ((size_t)(b * Cn + c0)) * Nn + n0;

    float part[8];
#pragma unroll
    for (int r = 0; r < 8; ++r) {
        int cl = (t >> 4) + r * 16;
        int nl = (t & 15) * 4;
        float4 v = *(const float4*)(xb + (size_t)cl * Nn + nl);
        float* tp = &tile[cl * 65 + nl];
        tp[0] = v.x; tp[1] = v.y; tp[2] = v.z; tp[3] = v.w;
        part[r] = (v.x + v.y) + (v.z + v.w);
    }
#pragma unroll
    for (int m = 1; m < 16; m <<= 1) {
#pragma unroll
        for (int r = 0; r < 8; ++r) part[r] += __shfl_xor(part[r], m);
    }
    if ((t & 15) == 0) {
#pragma unroll
        for (int r = 0; r < 8; ++r) {
            int cl = (t >> 4) + r * 16;
            sxp[(size_t)(b * Cn + c0 + cl) * 64 + blockIdx.x] = part[r];
        }
    }
    __syncthreads();
    u16* xtb = xt + ((size_t)(b * Nn + n0)) * Cn + c0;
#pragma unroll
    for (int r = 0; r < 4; ++r) {
        int nl = (t >> 4) + r * 16;
        int c8 = (t & 15) * 8;
        u16x8 hv;
#pragma unroll
        for (int i = 0; i < 8; ++i) hv[i] = f2bf(tile[(c8 + i) * 65 + nl]);
        *(u16x8*)(xtb + (size_t)nl * Cn + c8) = hv;
    }
}

// K1b: reduce 64 n-tile partials -> Sx[b*C+c]
__global__ __launch_bounds__(256) void k_sxred(
    const float* __restrict__ sxp, float* __restrict__ sx)
{
    int i = blockIdx.x * 256 + threadIdx.x;  // 0..8191
    const float4* p = (const float4*)(sxp + (size_t)i * 64);
    float s = 0.f;
#pragma unroll
    for (int j = 0; j < 16; ++j) {
        float4 v = p[j];
        s += (v.x + v.y) + (v.z + v.w);
    }
    sx[i] = s;
}

// K2: qy[b,o] = wq@y + bq ; sk[b,o] = wk@Sx + N*bk. One wave per output.
__global__ __launch_bounds__(256) void k_qk(
    const float* __restrict__ wq, const float* __restrict__ bq,
    const float* __restrict__ wk, const float* __restrict__ bk,
    const float* __restrict__ y, const float* __restrict__ sx,
    float* __restrict__ qy, float* __restrict__ sk)
{
    const int w = threadIdx.x >> 6, lane = threadIdx.x & 63;
    const int o = blockIdx.x * 4 + w;
    const int b = blockIdx.y;
    const int mode = blockIdx.z;
    const float* W = mode ? wk : wq;
    const float* vec = mode ? (sx + b * Cn) : (y + b * Cn);
    float sum = 0.f;
#pragma unroll
    for (int i = 0; i < 8; ++i) {
        int k2 = lane + i * 64;
        sum += W[(size_t)o * Cn + k2] * vec[k2];
    }
#pragma unroll
    for (int m = 1; m < 64; m <<= 1) sum += __shfl_xor(sum, m);
    if (lane == 0) {
        if (mode) sk[b * Cn + o] = sum + 4096.0f * bk[o];
        else      qy[b * Cn + o] = sum + bq[o];
    }
}

// K2b: wv_t[e,d] = bf16(wv[d,e]) via 64x64 LDS tile (coalesced both sides)
__global__ __launch_bounds__(256) void k_wvt(
    const float* __restrict__ wv, u16* __restrict__ wvt)
{
    __shared__ float tl[64 * 65];
    const int d0 = blockIdx.x * 64, e0 = blockIdx.y * 64;
    const int t = threadIdx.x;
#pragma unroll
    for (int r = 0; r < 4; ++r) {
        int d = (t >> 4) + r * 16, e4 = (t & 15) * 4;
        float4 v = *(const float4*)(wv + (size_t)(d0 + d) * Cn + e0 + e4);
        float* p = &tl[d * 65 + e4];
        p[0] = v.x; p[1] = v.y; p[2] = v.z; p[3] = v.w;
    }
    __syncthreads();
#pragma unroll
    for (int r = 0; r < 4; ++r) {
        int e = (t >> 4) + r * 16, d4 = (t & 15) * 4;
        ushort4 h;
        h.x = f2bf(tl[(d4 + 0) * 65 + e]);
        h.y = f2bf(tl[(d4 + 1) * 65 + e]);
        h.z = f2bf(tl[(d4 + 2) * 65 + e]);
        h.w = f2bf(tl[(d4 + 3) * 65 + e]);
        *(ushort4*)(wvt + (size_t)(e0 + e) * Cn + d0 + d4) = h;
    }
}

// K3: per (b,c) row: softmax_d(qy*sk) -> attn (bf16), beff = attn . bv (fp32)
__global__ __launch_bounds__(256) void k_softmax(
    const float* __restrict__ qy, const float* __restrict__ sk,
    const float* __restrict__ bv, u16* __restrict__ attn,
    float* __restrict__ beff)
{
    __shared__ float red[4], red2[4], red3[4];
    const int b = blockIdx.x >> 9, c = blockIdx.x & 511;
    const int t = threadIdx.x;
    const float q = qy[b * Cn + c];
    const float l0 = q * sk[b * Cn + t];
    const float l1 = q * sk[b * Cn + t + 256];
    float mx = fmaxf(l0, l1);
#pragma unroll
    for (int m = 1; m < 64; m <<= 1) mx = fmaxf(mx, __shfl_xor(mx, m));
    if ((t & 63) == 0) red[t >> 6] = mx;
    __syncthreads();
    mx = fmaxf(fmaxf(red[0], red[1]), fmaxf(red[2], red[3]));
    const float e0 = __expf(l0 - mx), e1 = __expf(l1 - mx);
    float s = e0 + e1;
#pragma unroll
    for (int m = 1; m < 64; m <<= 1) s += __shfl_xor(s, m);
    if ((t & 63) == 0) red2[t >> 6] = s;
    __syncthreads();
    s = red2[0] + red2[1] + red2[2] + red2[3];
    const float inv = 1.0f / s;
    const float a0 = e0 * inv, a1 = e1 * inv;
    u16* arow = attn + ((size_t)(b * Cn + c)) * Cn;
    arow[t] = f2bf(a0);
    arow[t + 256] = f2bf(a1);
    float pb = a0 * bv[t] + a1 * bv[t + 256];
#pragma unroll
    for (int m = 1; m < 64; m <<= 1) pb += __shfl_xor(pb, m);
    if ((t & 63) == 0) red3[t >> 6] = pb;
    __syncthreads();
    if (t == 0) beff[b * Cn + c] = red3[0] + red3[1] + red3[2] + red3[3];
}

// ---------------------------------------------------------------------------
// Shared MFMA GEMM: D[b] = A[b] (MxK, bf16, lda=K) * Bt[b]^T (Bt is NxK, bf16).
// 128x128 block tile, BK=32, 4 waves each 64x64 (4x4 of 16x16x32 MFMA).
// Staging via global_load_lds width=16 (m97 pattern).
// FINAL=1: out fp32 = gamma*(acc + beff[row]) + xres ; else out bf16.
// ---------------------------------------------------------------------------
template <int FINAL>
__global__ __launch_bounds__(256) void k_gemm(
    const u16* __restrict__ A, size_t strideA,
    const u16* __restrict__ Bt, size_t strideB,
    int N,
    u16* __restrict__ outBf, size_t strideOb,
    float* __restrict__ outF,
    const float* __restrict__ xres,
    const float* __restrict__ beff,
    const float* __restrict__ gamma)
{
    constexpr int K = 512;
    __shared__ u16 la[128 * 32];
    __shared__ u16 lb[128 * 32];
    const int b = blockIdx.z;
    const int m0 = blockIdx.y * 128;
    const int n0 = blockIdx.x * 128;
    A  += (size_t)b * strideA;
    Bt += (size_t)b * strideB;
    const int t = threadIdx.x;
    const int lane = t & 63;
    const int w = t >> 6;
    const int wm = (w >> 1) * 64, wn = (w & 1) * 64;
    const int l15 = lane & 15, quad = lane >> 4;

    f32x4 acc[4][4];
#pragma unroll
    for (int i = 0; i < 4; ++i)
#pragma unroll
        for (int j = 0; j < 4; ++j)
            acc[i][j] = (f32x4){0.f, 0.f, 0.f, 0.f};

    // glds mapping: wave w stages rows [w*16, w*16+16) and +64 of each tile.
    // lane l -> row rb + l/4, bf16 col (l&3)*8; LDS dest = base + lane*16B.
    const int rb = w * 16;
    const int lrow = lane >> 2;
    const int lcol = (lane & 3) * 8;

    for (int k0 = 0; k0 < K; k0 += 32) {
        __syncthreads();
        const u16* gA = A + (size_t)(m0 + rb + lrow) * K + k0 + lcol;
        glds16(gA, &la[rb * 32]);
        glds16(gA + (size_t)64 * K, &la[(rb + 64) * 32]);
        const u16* gB = Bt + (size_t)(n0 + rb + lrow) * K + k0 + lcol;
        glds16(gB, &lb[rb * 32]);
        glds16(gB + (size_t)64 * K, &lb[(rb + 64) * 32]);
        __syncthreads();

        bf16x8 af[4], bfr[4];
#pragma unroll
        for (int mi = 0; mi < 4; ++mi)
            af[mi] = *(const bf16x8*)&la[(wm + mi * 16 + l15) * 32 + quad * 8];
#pragma unroll
        for (int ni = 0; ni < 4; ++ni)
            bfr[ni] = *(const bf16x8*)&lb[(wn + ni * 16 + l15) * 32 + quad * 8];
#pragma unroll
        for (int mi = 0; mi < 4; ++mi)
#pragma unroll
            for (int ni = 0; ni < 4; ++ni)
                acc[mi][ni] = __builtin_amdgcn_mfma_f32_16x16x32_bf16(
                    af[mi], bfr[ni], acc[mi][ni], 0, 0, 0);
    }

    if (FINAL) {
        const float g = gamma[0];
#pragma unroll
        for (int mi = 0; mi < 4; ++mi) {
#pragma unroll
            for (int reg = 0; reg < 4; ++reg) {
                const int r = m0 + wm + mi * 16 + quad * 4 + reg;
                const float be = beff[b * Cn + r];
                const size_t base = ((size_t)(b * Cn + r)) * N;
#pragma unroll
                for (int ni = 0; ni < 4; ++ni) {
                    const int cidx = n0 + wn + ni * 16 + l15;
                    outF[base + cidx] = g * (acc[mi][ni][reg] + be) + xres[base + cidx];
                }
            }
        }
    } else {
#pragma unroll
        for (int mi = 0; mi < 4; ++mi) {
#pragma unroll
            for (int reg = 0; reg < 4; ++reg) {
                const int r = m0 + wm + mi * 16 + quad * 4 + reg;
                const size_t base = (size_t)b * strideOb + (size_t)r * N;
#pragma unroll
                for (int ni = 0; ni < 4; ++ni) {
                    const int cidx = n0 + wn + ni * 16 + l15;
                    outBf[base + cidx] = f2bf(acc[mi][ni][reg]);
                }
            }
        }
    }
}

// ---------------------------------------------------------------------------
extern "C" void kernel_launch(void* const* d_in, const int* in_sizes, int n_in,
                              void* d_out, int out_size, void* d_ws, size_t ws_size,
                              hipStream_t stream)
{
    const float* x     = (const float*)d_in[0];
    const float* y     = (const float*)d_in[1];
    const float* wq    = (const float*)d_in[2];
    const float* bq    = (const float*)d_in[3];
    const float* wk    = (const float*)d_in[4];
    const float* bk    = (const float*)d_in[5];
    const float* wv    = (const float*)d_in[6];
    const float* bv    = (const float*)d_in[7];
    const float* gamma = (const float*)d_in[8];
    float* out = (float*)d_out;

    char* ws = (char*)d_ws;
    u16*   xt   = (u16*)  (ws + 0);           // 67,108,864 B : x^T bf16 (B,N,C)
    float* sxp  = (float*)(ws + 67108864);    //  2,097,152 B : partial sums
    float* sx   = (float*)(ws + 69206016);    //     32,768 B
    float* qy   = (float*)(ws + 69238784);    //     32,768 B
    float* sk   = (float*)(ws + 69271552);    //     32,768 B
    float* beff = (float*)(ws + 69304320);    //     32,768 B
    u16*   attn = (u16*)  (ws + 69337088);    //  8,388,608 B : attn bf16
    u16*   wvt  = (u16*)  (ws + 77725696);    //    524,288 B : wv^T bf16
    u16*   weff = (u16*)  (ws + 78249984);    //  8,388,608 B : Weff bf16
    // total ~86.6 MB

    k_transpose<<<dim3(64, 4, Bn), dim3(256), 0, stream>>>(x, xt, sxp);
    k_sxred<<<dim3(32), dim3(256), 0, stream>>>(sxp, sx);
    k_wvt<<<dim3(8, 8), dim3(256), 0, stream>>>(wv, wvt);
    k_qk<<<dim3(128, Bn, 2), dim3(256), 0, stream>>>(wq, bq, wk, bk, y, sx, qy, sk);
    k_softmax<<<dim3(Bn * Cn), dim3(256), 0, stream>>>(qy, sk, bv, attn, beff);
    // Weff[b] = attn[b] @ wv  (as A * wv_t^T), output bf16
    k_gemm<0><<<dim3(4, 4, Bn), dim3(256), 0, stream>>>(
        attn, (size_t)Cn * Cn, wvt, (size_t)0, Cn,
        weff, (size_t)Cn * Cn, nullptr, nullptr, nullptr, nullptr);
    // out[b] = gamma * (Weff[b] @ x[b] + beff) + x
    k_gemm<1><<<dim3(32, 4, Bn), dim3(256), 0, stream>>>(
        weff, (size_t)Cn * Cn, xt, (size_t)Nn * Cn, Nn,
        nullptr, (size_t)0, out, x, beff, gamma);
}

// Round 3
// 351.617 us; speedup vs baseline: 1.0421x; 1.0271x over previous
//
#include <hip/hip_runtime.h>
#include <hip/hip_bf16.h>

#define Bn 16
#define Cn 512
#define Nn 4096

typedef unsigned short u16;
typedef __bf16 bf16x8 __attribute__((ext_vector_type(8)));
typedef float f32x4 __attribute__((ext_vector_type(4)));
typedef unsigned short u16x8 __attribute__((ext_vector_type(8)));

__device__ __forceinline__ u16 f2bf(float f) {
    __hip_bfloat16 h = __float2bfloat16(f);
    return *reinterpret_cast<u16*>(&h);
}

// async global->LDS, 16B per lane; LDS dest is wave-uniform base + lane*16
__device__ __forceinline__ void glds16(const u16* g, u16* l) {
    __builtin_amdgcn_global_load_lds(
        (const __attribute__((address_space(1))) void*)g,
        (__attribute__((address_space(3))) void*)l, 16, 0, 0);
}

// ---------------------------------------------------------------------------
// K1: x (B,C,N) fp32 -> x_t (B,N,C) bf16, plus per-(b,c) partial sums over the
// 64-wide n-tile. 128c x 64n tile: 256B segments on both read and write sides.
// ---------------------------------------------------------------------------
__global__ __launch_bounds__(256) void k_transpose(
    const float* __restrict__ x, u16* __restrict__ xt, float* __restrict__ sxp)
{
    __shared__ float tile[128 * 65];
    const int b = blockIdx.z, c0 = blockIdx.y * 128, n0 = blockIdx.x * 64;
    const int t = threadIdx.x;
    const float* xb = x + ((size_t)(b * Cn + c0)) * Nn + n0;

    float part[8];
#pragma unroll
    for (int r = 0; r < 8; ++r) {
        int cl = (t >> 4) + r * 16;
        int nl = (t & 15) * 4;
        float4 v = *(const float4*)(xb + (size_t)cl * Nn + nl);
        float* tp = &tile[cl * 65 + nl];
        tp[0] = v.x; tp[1] = v.y; tp[2] = v.z; tp[3] = v.w;
        part[r] = (v.x + v.y) + (v.z + v.w);
    }
#pragma unroll
    for (int m = 1; m < 16; m <<= 1) {
#pragma unroll
        for (int r = 0; r < 8; ++r) part[r] += __shfl_xor(part[r], m);
    }
    if ((t & 15) == 0) {
#pragma unroll
        for (int r = 0; r < 8; ++r) {
            int cl = (t >> 4) + r * 16;
            sxp[(size_t)(b * Cn + c0 + cl) * 64 + blockIdx.x] = part[r];
        }
    }
    __syncthreads();
    u16* xtb = xt + ((size_t)(b * Nn + n0)) * Cn + c0;
#pragma unroll
    for (int r = 0; r < 4; ++r) {
        int nl = (t >> 4) + r * 16;
        int c8 = (t & 15) * 8;
        u16x8 hv;
#pragma unroll
        for (int i = 0; i < 8; ++i) hv[i] = f2bf(tile[(c8 + i) * 65 + nl]);
        *(u16x8*)(xtb + (size_t)nl * Cn + c8) = hv;
    }
}

// K1b: reduce 64 n-tile partials -> Sx[b*C+c]
__global__ __launch_bounds__(256) void k_sxred(
    const float* __restrict__ sxp, float* __restrict__ sx)
{
    int i = blockIdx.x * 256 + threadIdx.x;  // 0..8191
    const float4* p = (const float4*)(sxp + (size_t)i * 64);
    float s = 0.f;
#pragma unroll
    for (int j = 0; j < 16; ++j) {
        float4 v = p[j];
        s += (v.x + v.y) + (v.z + v.w);
    }
    sx[i] = s;
}

// K2: qy[b,o] = wq@y + bq ; sk[b,o] = wk@Sx + N*bk. One wave per output.
__global__ __launch_bounds__(256) void k_qk(
    const float* __restrict__ wq, const float* __restrict__ bq,
    const float* __restrict__ wk, const float* __restrict__ bk,
    const float* __restrict__ y, const float* __restrict__ sx,
    float* __restrict__ qy, float* __restrict__ sk)
{
    const int w = threadIdx.x >> 6, lane = threadIdx.x & 63;
    const int o = blockIdx.x * 4 + w;
    const int b = blockIdx.y;
    const int mode = blockIdx.z;
    const float* W = mode ? wk : wq;
    const float* vec = mode ? (sx + b * Cn) : (y + b * Cn);
    float sum = 0.f;
#pragma unroll
    for (int i = 0; i < 8; ++i) {
        int k2 = lane + i * 64;
        sum += W[(size_t)o * Cn + k2] * vec[k2];
    }
#pragma unroll
    for (int m = 1; m < 64; m <<= 1) sum += __shfl_xor(sum, m);
    if (lane == 0) {
        if (mode) sk[b * Cn + o] = sum + 4096.0f * bk[o];
        else      qy[b * Cn + o] = sum + bq[o];
    }
}

// K2b: wv_t[e,d] = bf16(wv[d,e]) via 64x64 LDS tile (coalesced both sides)
__global__ __launch_bounds__(256) void k_wvt(
    const float* __restrict__ wv, u16* __restrict__ wvt)
{
    __shared__ float tl[64 * 65];
    const int d0 = blockIdx.x * 64, e0 = blockIdx.y * 64;
    const int t = threadIdx.x;
#pragma unroll
    for (int r = 0; r < 4; ++r) {
        int d = (t >> 4) + r * 16, e4 = (t & 15) * 4;
        float4 v = *(const float4*)(wv + (size_t)(d0 + d) * Cn + e0 + e4);
        float* p = &tl[d * 65 + e4];
        p[0] = v.x; p[1] = v.y; p[2] = v.z; p[3] = v.w;
    }
    __syncthreads();
#pragma unroll
    for (int r = 0; r < 4; ++r) {
        int e = (t >> 4) + r * 16, d4 = (t & 15) * 4;
        ushort4 h;
        h.x = f2bf(tl[(d4 + 0) * 65 + e]);
        h.y = f2bf(tl[(d4 + 1) * 65 + e]);
        h.z = f2bf(tl[(d4 + 2) * 65 + e]);
        h.w = f2bf(tl[(d4 + 3) * 65 + e]);
        *(ushort4*)(wvt + (size_t)(e0 + e) * Cn + d0 + d4) = h;
    }
}

// K3: per (b,c) row: softmax_d(qy*sk) -> attn (bf16), beff = attn . bv (fp32)
__global__ __launch_bounds__(256) void k_softmax(
    const float* __restrict__ qy, const float* __restrict__ sk,
    const float* __restrict__ bv, u16* __restrict__ attn,
    float* __restrict__ beff)
{
    __shared__ float red[4], red2[4], red3[4];
    const int b = blockIdx.x >> 9, c = blockIdx.x & 511;
    const int t = threadIdx.x;
    const float q = qy[b * Cn + c];
    const float l0 = q * sk[b * Cn + t];
    const float l1 = q * sk[b * Cn + t + 256];
    float mx = fmaxf(l0, l1);
#pragma unroll
    for (int m = 1; m < 64; m <<= 1) mx = fmaxf(mx, __shfl_xor(mx, m));
    if ((t & 63) == 0) red[t >> 6] = mx;
    __syncthreads();
    mx = fmaxf(fmaxf(red[0], red[1]), fmaxf(red[2], red[3]));
    const float e0 = __expf(l0 - mx), e1 = __expf(l1 - mx);
    float s = e0 + e1;
#pragma unroll
    for (int m = 1; m < 64; m <<= 1) s += __shfl_xor(s, m);
    if ((t & 63) == 0) red2[t >> 6] = s;
    __syncthreads();
    s = red2[0] + red2[1] + red2[2] + red2[3];
    const float inv = 1.0f / s;
    const float a0 = e0 * inv, a1 = e1 * inv;
    u16* arow = attn + ((size_t)(b * Cn + c)) * Cn;
    arow[t] = f2bf(a0);
    arow[t + 256] = f2bf(a1);
    float pb = a0 * bv[t] + a1 * bv[t + 256];
#pragma unroll
    for (int m = 1; m < 64; m <<= 1) pb += __shfl_xor(pb, m);
    if ((t & 63) == 0) red3[t >> 6] = pb;
    __syncthreads();
    if (t == 0) beff[b * Cn + c] = red3[0] + red3[1] + red3[2] + red3[3];
}

// ---------------------------------------------------------------------------
// Shared MFMA GEMM: D[b] = A[b] (MxK, bf16, lda=K) * Bt[b]^T (Bt is NxK, bf16).
// 128x128 block tile, BK=64 (8 barrier iters), 4 waves each 64x64.
// Staging via global_load_lds w=16 with XOR-swizzled k-groups:
//   LDS physical group pg = logical_group ^ (row & 7)  (group = 8 bf16 = 16B)
// -> fragment ds_read_b128 banks spread 2-way (free) with zero padding.
// FINAL=1: LDS-staged float4 epilogue: out fp32 = gamma*(acc+beff[r]) + xres.
// ---------------------------------------------------------------------------
template <int FINAL>
__global__ __launch_bounds__(256) void k_gemm(
    const u16* __restrict__ A, size_t strideA,
    const u16* __restrict__ Bt, size_t strideB,
    int N,
    u16* __restrict__ outBf, size_t strideOb,
    float* __restrict__ outF,
    const float* __restrict__ xres,
    const float* __restrict__ beff,
    const float* __restrict__ gamma)
{
    constexpr int K = 512;
    __shared__ float smem_f[8448];          // 33,792 B: K-loop 32KB / epi 33KB
    u16* la = (u16*)smem_f;                 // [128*64] bf16
    u16* lb = la + 128 * 64;
    const int b = blockIdx.z;
    const int m0 = blockIdx.y * 128;
    const int n0 = blockIdx.x * 128;
    A  += (size_t)b * strideA;
    Bt += (size_t)b * strideB;
    const int t = threadIdx.x;
    const int lane = t & 63;
    const int w = t >> 6;
    const int wm = (w >> 1) * 64, wn = (w & 1) * 64;
    const int l15 = lane & 15, quad = lane >> 4;

    f32x4 acc[4][4];
#pragma unroll
    for (int i = 0; i < 4; ++i)
#pragma unroll
        for (int j = 0; j < 4; ++j)
            acc[i][j] = (f32x4){0.f, 0.f, 0.f, 0.f};

    // staging decomposition: slot = w*256 + j*64 + lane (1024 slots of 16B)
    const int srow8 = lane >> 3;                 // 0..7
    const int lgcol = ((lane & 7) ^ srow8) * 8;  // logical k-col (swizzled)

    for (int k0 = 0; k0 < K; k0 += 64) {
        __syncthreads();
#pragma unroll
        for (int j = 0; j < 4; ++j) {
            const int row = w * 32 + j * 8 + srow8;
            const int sb = (w * 256 + j * 64) * 8;   // u16 offset of slot base
            glds16(A  + (size_t)(m0 + row) * K + k0 + lgcol, la + sb);
            glds16(Bt + (size_t)(n0 + row) * K + k0 + lgcol, lb + sb);
        }
        __syncthreads();

#pragma unroll
        for (int kk2 = 0; kk2 < 2; ++kk2) {
            bf16x8 af[4], bfr[4];
#pragma unroll
            for (int mi = 0; mi < 4; ++mi) {
                const int r = wm + mi * 16 + l15;
                const int pg = ((kk2 << 2) + quad) ^ (l15 & 7);
                af[mi] = *(const bf16x8*)&la[r * 64 + pg * 8];
            }
#pragma unroll
            for (int ni = 0; ni < 4; ++ni) {
                const int r = wn + ni * 16 + l15;
                const int pg = ((kk2 << 2) + quad) ^ (l15 & 7);
                bfr[ni] = *(const bf16x8*)&lb[r * 64 + pg * 8];
            }
#pragma unroll
            for (int mi = 0; mi < 4; ++mi)
#pragma unroll
                for (int ni = 0; ni < 4; ++ni)
                    acc[mi][ni] = __builtin_amdgcn_mfma_f32_16x16x32_bf16(
                        af[mi], bfr[ni], acc[mi][ni], 0, 0, 0);
        }
    }

    if (FINAL) {
        const float g = gamma[0];
        float* lc = smem_f;                  // 64 rows x stride 132 fp32
#pragma unroll
        for (int h = 0; h < 2; ++h) {
            __syncthreads();
            if ((w >> 1) == h) {
#pragma unroll
                for (int mi = 0; mi < 4; ++mi)
#pragma unroll
                    for (int reg = 0; reg < 4; ++reg) {
                        const int rl = mi * 16 + quad * 4 + reg;
#pragma unroll
                        for (int ni = 0; ni < 4; ++ni)
                            lc[rl * 132 + wn + ni * 16 + l15] = acc[mi][ni][reg];
                    }
            }
            __syncthreads();
            const int rb = h * 64;
#pragma unroll
            for (int rr = 0; rr < 8; ++rr) {
                const int rl = rr * 8 + (t >> 5);
                const int c4 = (t & 31) * 4;
                float4 v = *(float4*)&lc[rl * 132 + c4];
                const int r = m0 + rb + rl;
                const float be = beff[b * Cn + r];
                const size_t base = ((size_t)(b * Cn + r)) * N + n0 + c4;
                float4 xr = *(const float4*)(xres + base);
                float4 o;
                o.x = g * (v.x + be) + xr.x;
                o.y = g * (v.y + be) + xr.y;
                o.z = g * (v.z + be) + xr.z;
                o.w = g * (v.w + be) + xr.w;
                *(float4*)(outF + base) = o;
            }
        }
    } else {
#pragma unroll
        for (int mi = 0; mi < 4; ++mi) {
#pragma unroll
            for (int reg = 0; reg < 4; ++reg) {
                const int r = m0 + wm + mi * 16 + quad * 4 + reg;
                const size_t base = (size_t)b * strideOb + (size_t)r * N;
#pragma unroll
                for (int ni = 0; ni < 4; ++ni) {
                    const int cidx = n0 + wn + ni * 16 + l15;
                    outBf[base + cidx] = f2bf(acc[mi][ni][reg]);
                }
            }
        }
    }
}

// ---------------------------------------------------------------------------
extern "C" void kernel_launch(void* const* d_in, const int* in_sizes, int n_in,
                              void* d_out, int out_size, void* d_ws, size_t ws_size,
                              hipStream_t stream)
{
    const float* x     = (const float*)d_in[0];
    const float* y     = (const float*)d_in[1];
    const float* wq    = (const float*)d_in[2];
    const float* bq    = (const float*)d_in[3];
    const float* wk    = (const float*)d_in[4];
    const float* bk    = (const float*)d_in[5];
    const float* wv    = (const float*)d_in[6];
    const float* bv    = (const float*)d_in[7];
    const float* gamma = (const float*)d_in[8];
    float* out = (float*)d_out;

    char* ws = (char*)d_ws;
    u16*   xt   = (u16*)  (ws + 0);           // 67,108,864 B : x^T bf16 (B,N,C)
    float* sxp  = (float*)(ws + 67108864);    //  2,097,152 B : partial sums
    float* sx   = (float*)(ws + 69206016);    //     32,768 B
    float* qy   = (float*)(ws + 69238784);    //     32,768 B
    float* sk   = (float*)(ws + 69271552);    //     32,768 B
    float* beff = (float*)(ws + 69304320);    //     32,768 B
    u16*   attn = (u16*)  (ws + 69337088);    //  8,388,608 B : attn bf16
    u16*   wvt  = (u16*)  (ws + 77725696);    //    524,288 B : wv^T bf16
    u16*   weff = (u16*)  (ws + 78249984);    //  8,388,608 B : Weff bf16
    // total ~86.6 MB

    k_transpose<<<dim3(64, 4, Bn), dim3(256), 0, stream>>>(x, xt, sxp);
    k_sxred<<<dim3(32), dim3(256), 0, stream>>>(sxp, sx);
    k_wvt<<<dim3(8, 8), dim3(256), 0, stream>>>(wv, wvt);
    k_qk<<<dim3(128, Bn, 2), dim3(256), 0, stream>>>(wq, bq, wk, bk, y, sx, qy, sk);
    k_softmax<<<dim3(Bn * Cn), dim3(256), 0, stream>>>(qy, sk, bv, attn, beff);
    // Weff[b] = attn[b] @ wv  (as A * wv_t^T), output bf16
    k_gemm<0><<<dim3(4, 4, Bn), dim3(256), 0, stream>>>(
        attn, (size_t)Cn * Cn, wvt, (size_t)0, Cn,
        weff, (size_t)Cn * Cn, nullptr, nullptr, nullptr, nullptr);
    // out[b] = gamma * (Weff[b] @ x[b] + beff) + x
    k_gemm<1><<<dim3(32, 4, Bn), dim3(256), 0, stream>>>(
        weff, (size_t)Cn * Cn, xt, (size_t)Nn * Cn, Nn,
        nullptr, (size_t)0, out, x, beff, gamma);
}